// Round 14
// baseline (606.110 us; speedup 1.0000x reference)
//
#include <hip/hip_runtime.h>

// Problem constants
#define Bn   8
#define Sn   1024
#define Dn   1024
#define Rn   256
#define NHn  16
#define DHn  64
#define NKn  4096
#define TOK  (Bn*Sn)        // 8192 tokens
#define EPE  (Dn*Rn)        // 262144 elements per expert table entry
#define TDN  3072           // merged QKV row stride
#define BPAD 44             // Bs row stride (22 dwords; 8-row group == 16 mod 32)

typedef __attribute__((ext_vector_type(8))) short short8;   // 8 bf16 (4 VGPR)
typedef __attribute__((ext_vector_type(4))) short short4v;  // 8B
typedef __attribute__((ext_vector_type(4))) float f32x4;
typedef __attribute__((ext_vector_type(4))) unsigned short ushort4v;
typedef unsigned short ush;

__device__ inline ush f2bf(float f) {
    union { float f; unsigned u; } v; v.f = f;
    unsigned r = v.u + 0x7fffu + ((v.u >> 16) & 1u);   // round-to-nearest-even
    return (ush)(r >> 16);
}
__device__ inline float bf2f(ush h) {
    union { unsigned u; float f; } v; v.u = ((unsigned)h) << 16;
    return v.f;
}
__device__ inline void f2bf_split(float f, ush& hi, ush& lo) {
    hi = f2bf(f);
    lo = f2bf(f - bf2f(hi));
}
__device__ inline short8 cat8(short4v a, short4v b) {
    short8 r;
    r[0]=a[0]; r[1]=a[1]; r[2]=a[2]; r[3]=a[3];
    r[4]=b[0]; r[5]=b[1]; r[6]=b[2]; r[7]=b[3];
    return r;
}

// ======================================================================
// Fused conversions: three tensors in one launch (x, Wo, kK).
// ======================================================================
__global__ __launch_bounds__(256) void convert3(
    const float* __restrict__ s0, ush* __restrict__ h0, ush* __restrict__ l0, long long n40,
    const float* __restrict__ s1, ush* __restrict__ h1, ush* __restrict__ l1, long long n41,
    const float* __restrict__ s2, ush* __restrict__ h2, ush* __restrict__ l2, long long n42)
{
    long long i = (long long)blockIdx.x*256 + threadIdx.x;
    const float* s; ush* h; ush* l;
    if (i < n40) { s = s0; h = h0; l = l0; }
    else if (i < n40 + n41) { i -= n40; s = s1; h = h1; l = l1; }
    else { i -= n40 + n41; if (i >= n42) return; s = s2; h = h2; l = l2; }
    float4 f = *(const float4*)&s[i*4];
    float vals[4] = {f.x, f.y, f.z, f.w};
    ushort4v hv, lv;
#pragma unroll
    for (int e = 0; e < 4; ++e) { ush a, b2; f2bf_split(vals[e], a, b2); hv[e] = a; lv[e] = b2; }
    *(ushort4v*)&h[i*4] = hv;
    *(ushort4v*)&l[i*4] = lv;
}

// 5 router weight matrices (each 64x1024) -> concat planes. grid (64,5).
__global__ __launch_bounds__(256) void convert_w5(
    const float* __restrict__ w0, const float* __restrict__ w1,
    const float* __restrict__ w2, const float* __restrict__ w3,
    const float* __restrict__ w4, ush* __restrict__ hi, ush* __restrict__ lo)
{
    int y = blockIdx.y;
    const float* srcs[5] = {w0, w1, w2, w3, w4};
    const float* s = srcs[y];
    long long i = (long long)blockIdx.x*256 + threadIdx.x;   // < 16384
    float4 f = *(const float4*)&s[i*4];
    float vals[4] = {f.x, f.y, f.z, f.w};
    ushort4v hv, lv;
#pragma unroll
    for (int e = 0; e < 4; ++e) { ush a, b2; f2bf_split(vals[e], a, b2); hv[e] = a; lv[e] = b2; }
    size_t dst = (size_t)y*64*Dn + i*4;
    *(ushort4v*)&hi[dst] = hv;
    *(ushort4v*)&lo[dst] = lv;
}

// ======================================================================
// Pre-split bf16 MFMA GEMM, tile 128x64 (BK=32), 4 waves (2x2).
// Bs stride BPAD=44 (conflict-fixed); all Bs traffic via b64 pairs.
// outMode: 0 f32->C0; 1 bf16->C0; 2 hi->C0,lo->C1.
// gridSwap: 0 -> (x=col,y=row); 1 -> (x=row,y=col)  [A-L2/XCD locality]
// ======================================================================
__global__ __launch_bounds__(256) void gemm_pre(
    const ush* __restrict__ Ahi, const ush* __restrict__ Alo,
    const ush* __restrict__ Bhi, const ush* __restrict__ Blo,
    void* __restrict__ C0, void* __restrict__ C1,
    int M, int N, int K, long long sA, long long sB, long long sC,
    float alpha, int bTrans, int passes, int outMode, int gridSwap)
{
    Ahi += (size_t)blockIdx.z * sA;
    if (Alo) Alo += (size_t)blockIdx.z * sA;
    Bhi += (size_t)blockIdx.z * sB;
    if (Blo) Blo += (size_t)blockIdx.z * sB;
    __shared__ __align__(16) ush AsH[128][40];
    __shared__ __align__(16) ush AsL[128][40];
    __shared__ __align__(16) ush BsH[64][BPAD];
    __shared__ __align__(16) ush BsL[64][BPAD];
    int tid = threadIdx.x;
    int wave = tid >> 6, lane = tid & 63;
    int lr = lane & 15, lg = lane >> 4;
    int wm = (wave >> 1)*64, wn = (wave & 1)*32;
    int row0 = (gridSwap ? blockIdx.x : blockIdx.y)*128;
    int col0 = (gridSwap ? blockIdx.y : blockIdx.x)*64;

    f32x4 acc[4][2];
#pragma unroll
    for (int i = 0; i < 4; ++i)
#pragma unroll
        for (int j = 0; j < 2; ++j) acc[i][j] = (f32x4){0.f,0.f,0.f,0.f};

    for (int k0 = 0; k0 < K; k0 += 32) {
        __syncthreads();
#pragma unroll
        for (int g = 0; g < 2; ++g) {
            int idx = tid + g*256;
            int m2 = idx >> 2, kk = (idx & 3)*8;
            size_t so = (size_t)(row0 + m2)*K + k0 + kk;
            *(short8*)&AsH[m2][kk] = *(const short8*)&Ahi[so];
            if (passes >= 2) *(short8*)&AsL[m2][kk] = *(const short8*)&Alo[so];
        }
        if (!bTrans) {                       // B is [N][K]: copy via b64 pairs
            int n2 = tid >> 2, kk = (tid & 3)*8;
            size_t so = (size_t)(col0 + n2)*K + k0 + kk;
            *(short4v*)&BsH[n2][kk]     = *(const short4v*)&Bhi[so];
            *(short4v*)&BsH[n2][kk + 4] = *(const short4v*)&Bhi[so + 4];
            if (passes >= 3) {
                *(short4v*)&BsL[n2][kk]     = *(const short4v*)&Blo[so];
                *(short4v*)&BsL[n2][kk + 4] = *(const short4v*)&Blo[so + 4];
            }
        } else {                             // B is [K][N]: transpose copy
            int kk = tid >> 3, n0 = (tid & 7)*8;
            size_t so = (size_t)(k0 + kk)*N + col0 + n0;
            short8 wh = *(const short8*)&Bhi[so];
#pragma unroll
            for (int e = 0; e < 8; ++e) BsH[n0+e][kk] = (ush)wh[e];
            if (passes >= 3) {
                short8 wl = *(const short8*)&Blo[so];
#pragma unroll
                for (int e = 0; e < 8; ++e) BsL[n0+e][kk] = (ush)wl[e];
            }
        }
        __syncthreads();
        short8 afH[4], bfH[2];
#pragma unroll
        for (int i = 0; i < 4; ++i) afH[i] = *(const short8*)&AsH[wm + i*16 + lr][lg*8];
#pragma unroll
        for (int j = 0; j < 2; ++j)
            bfH[j] = cat8(*(const short4v*)&BsH[wn + j*16 + lr][lg*8],
                          *(const short4v*)&BsH[wn + j*16 + lr][lg*8 + 4]);
#pragma unroll
        for (int i = 0; i < 4; ++i)
#pragma unroll
            for (int j = 0; j < 2; ++j)
                acc[i][j] = __builtin_amdgcn_mfma_f32_16x16x32_bf16(afH[i], bfH[j], acc[i][j], 0, 0, 0);
        if (passes >= 2) {
            short8 afL[4];
#pragma unroll
            for (int i = 0; i < 4; ++i) afL[i] = *(const short8*)&AsL[wm + i*16 + lr][lg*8];
#pragma unroll
            for (int i = 0; i < 4; ++i)
#pragma unroll
                for (int j = 0; j < 2; ++j)
                    acc[i][j] = __builtin_amdgcn_mfma_f32_16x16x32_bf16(afL[i], bfH[j], acc[i][j], 0, 0, 0);
        }
        if (passes >= 3) {
            short8 bfL[2];
#pragma unroll
            for (int j = 0; j < 2; ++j)
                bfL[j] = cat8(*(const short4v*)&BsL[wn + j*16 + lr][lg*8],
                              *(const short4v*)&BsL[wn + j*16 + lr][lg*8 + 4]);
#pragma unroll
            for (int i = 0; i < 4; ++i)
#pragma unroll
                for (int j = 0; j < 2; ++j)
                    acc[i][j] = __builtin_amdgcn_mfma_f32_16x16x32_bf16(afH[i], bfL[j], acc[i][j], 0, 0, 0);
        }
    }
#pragma unroll
    for (int i = 0; i < 4; ++i)
#pragma unroll
        for (int j = 0; j < 2; ++j)
#pragma unroll
            for (int r = 0; r < 4; ++r) {
                size_t eo = (size_t)(row0 + wm + i*16 + lg*4 + r)*N + col0 + wn + j*16 + lr;
                float val = acc[i][j][r] * alpha;
                if (outMode == 0) {
                    ((float*)C0 + (size_t)blockIdx.z*sC)[eo] = val;
                } else if (outMode == 1) {
                    ((ush*)C0 + (size_t)blockIdx.z*sC)[eo] = f2bf(val);
                } else {
                    ush h, l; f2bf_split(val, h, l);
                    ((ush*)C0 + (size_t)blockIdx.z*sC)[eo] = h;
                    ((ush*)C1 + (size_t)blockIdx.z*sC)[eo] = l;
                }
            }
}

// ======================================================================
// 64x64-tile GEMM (4 waves of 32x32), Bs stride BPAD, b64 B-traffic.
// mode 0: f32 -> C0 (width N). mode 1 (h+hm): cols<N/2 -> split planes
// C0/C1 (width N/2); cols>=N/2 -> f32 C2 + hi C3 (width N/2).
// ======================================================================
__global__ __launch_bounds__(256) void gemm64(
    const ush* __restrict__ Ahi, const ush* __restrict__ Alo,
    const ush* __restrict__ Bhi, const ush* __restrict__ Blo,
    void* __restrict__ C0, void* __restrict__ C1,
    void* __restrict__ C2, void* __restrict__ C3,
    int N, int K, long long sA, long long sB, long long sCL, long long sCR,
    float alpha, int bTrans, int passes, int mode)
{
    Ahi += (size_t)blockIdx.z * sA;
    if (Alo) Alo += (size_t)blockIdx.z * sA;
    Bhi += (size_t)blockIdx.z * sB;
    if (Blo) Blo += (size_t)blockIdx.z * sB;
    __shared__ __align__(16) ush AsH[64][40];
    __shared__ __align__(16) ush AsL[64][40];
    __shared__ __align__(16) ush BsH[64][BPAD];
    __shared__ __align__(16) ush BsL[64][BPAD];
    int tid = threadIdx.x;
    int wave = tid >> 6, lane = tid & 63;
    int lr = lane & 15, lg = lane >> 4;
    int wm = (wave >> 1)*32, wn = (wave & 1)*32;
    int row0 = blockIdx.y*64, col0 = blockIdx.x*64;

    f32x4 acc[2][2];
#pragma unroll
    for (int i = 0; i < 2; ++i)
#pragma unroll
        for (int j = 0; j < 2; ++j) acc[i][j] = (f32x4){0.f,0.f,0.f,0.f};

    for (int k0 = 0; k0 < K; k0 += 32) {
        __syncthreads();
        {   // stage A 64x32: one short8 per thread
            int m2 = tid >> 2, kk = (tid & 3)*8;
            size_t so = (size_t)(row0 + m2)*K + k0 + kk;
            *(short8*)&AsH[m2][kk] = *(const short8*)&Ahi[so];
            if (passes >= 2) *(short8*)&AsL[m2][kk] = *(const short8*)&Alo[so];
        }
        if (!bTrans) {
            int n2 = tid >> 2, kk = (tid & 3)*8;
            size_t so = (size_t)(col0 + n2)*K + k0 + kk;
            *(short4v*)&BsH[n2][kk]     = *(const short4v*)&Bhi[so];
            *(short4v*)&BsH[n2][kk + 4] = *(const short4v*)&Bhi[so + 4];
            if (passes >= 3) {
                *(short4v*)&BsL[n2][kk]     = *(const short4v*)&Blo[so];
                *(short4v*)&BsL[n2][kk + 4] = *(const short4v*)&Blo[so + 4];
            }
        } else {
            int kk = tid >> 3, n0 = (tid & 7)*8;
            size_t so = (size_t)(k0 + kk)*N + col0 + n0;
            short8 wh = *(const short8*)&Bhi[so];
#pragma unroll
            for (int e = 0; e < 8; ++e) BsH[n0+e][kk] = (ush)wh[e];
            if (passes >= 3) {
                short8 wl = *(const short8*)&Blo[so];
#pragma unroll
                for (int e = 0; e < 8; ++e) BsL[n0+e][kk] = (ush)wl[e];
            }
        }
        __syncthreads();
        short8 afH[2], bfH[2];
#pragma unroll
        for (int i = 0; i < 2; ++i) afH[i] = *(const short8*)&AsH[wm + i*16 + lr][lg*8];
#pragma unroll
        for (int j = 0; j < 2; ++j)
            bfH[j] = cat8(*(const short4v*)&BsH[wn + j*16 + lr][lg*8],
                          *(const short4v*)&BsH[wn + j*16 + lr][lg*8 + 4]);
#pragma unroll
        for (int i = 0; i < 2; ++i)
#pragma unroll
            for (int j = 0; j < 2; ++j)
                acc[i][j] = __builtin_amdgcn_mfma_f32_16x16x32_bf16(afH[i], bfH[j], acc[i][j], 0, 0, 0);
        if (passes >= 2) {
            short8 afL[2];
#pragma unroll
            for (int i = 0; i < 2; ++i) afL[i] = *(const short8*)&AsL[wm + i*16 + lr][lg*8];
#pragma unroll
            for (int i = 0; i < 2; ++i)
#pragma unroll
                for (int j = 0; j < 2; ++j)
                    acc[i][j] = __builtin_amdgcn_mfma_f32_16x16x32_bf16(afL[i], bfH[j], acc[i][j], 0, 0, 0);
        }
        if (passes >= 3) {
            short8 bfL[2];
#pragma unroll
            for (int j = 0; j < 2; ++j)
                bfL[j] = cat8(*(const short4v*)&BsL[wn + j*16 + lr][lg*8],
                              *(const short4v*)&BsL[wn + j*16 + lr][lg*8 + 4]);
#pragma unroll
            for (int i = 0; i < 2; ++i)
#pragma unroll
                for (int j = 0; j < 2; ++j)
                    acc[i][j] = __builtin_amdgcn_mfma_f32_16x16x32_bf16(afH[i], bfL[j], acc[i][j], 0, 0, 0);
        }
    }
    int Nh = N >> 1;
#pragma unroll
    for (int i = 0; i < 2; ++i)
#pragma unroll
        for (int j = 0; j < 2; ++j)
#pragma unroll
            for (int r = 0; r < 4; ++r) {
                int grow = row0 + wm + i*16 + lg*4 + r;
                int gcol = col0 + wn + j*16 + lr;
                float val = acc[i][j][r] * alpha;
                if (mode == 0) {
                    ((float*)C0 + (size_t)blockIdx.z*sCL)[(size_t)grow*N + gcol] = val;
                } else {
                    if (gcol < Nh) {
                        ush h, l; f2bf_split(val, h, l);
                        size_t eo = (size_t)blockIdx.z*sCL + (size_t)grow*Nh + gcol;
                        ((ush*)C0)[eo] = h;
                        ((ush*)C1)[eo] = l;
                    } else {
                        size_t eo = (size_t)blockIdx.z*sCR + (size_t)grow*Nh + (gcol - Nh);
                        ((float*)C2)[eo] = val;
                        ((ush*)C3)[eo] = f2bf(val);
                    }
                }
            }
}

// ======================================================================
// Router post: softmax(logits)*importance, partial-sum over 256-token
// chunks. logits [8192][320]; partial [5][8][4][64].
// ======================================================================
__global__ __launch_bounds__(256) void router_post(
    const float* __restrict__ logits, const float* __restrict__ imp,
    float* __restrict__ partial)
{
    int blk = blockIdx.x;                 // 0..159
    int chunk = blk & 3, b = (blk >> 2) & 7, r = blk >> 5;
    int tid = threadIdx.x, lane = tid & 63, wv = tid >> 6;
    float acc = 0.f;
    for (int i = wv; i < 256; i += 4) {
        int t = b*1024 + chunk*256 + i;
        float lgv = logits[(size_t)t*320 + r*64 + lane];
        float mx = lgv;
        for (int off = 32; off >= 1; off >>= 1) mx = fmaxf(mx, __shfl_xor(mx, off));
        float e = __expf(lgv - mx);
        float s = e;
        for (int off = 32; off >= 1; off >>= 1) s += __shfl_xor(s, off);
        acc += imp[t] * e / s;
    }
    __shared__ float red[4][64];
    red[wv][lane] = acc;
    __syncthreads();
    if (tid < 64)
        partial[((size_t)(r*8 + b)*4 + chunk)*64 + tid]
            = red[0][tid] + red[1][tid] + red[2][tid] + red[3][tid];
}

// Normalize, top-k (k=16 for routers 0,4; k=8 for 1,2,3), renormalize.
__global__ void topk_router(const float* __restrict__ partial,
                            float* __restrict__ tw, int* __restrict__ ti)
{
    int rb = blockIdx.x;           // r*8+b
    int r  = rb >> 3;
    int lane = threadIdx.x;        // 64 threads = 1 wave
    float v = partial[((size_t)rb*4 + 0)*64 + lane] + partial[((size_t)rb*4 + 1)*64 + lane]
            + partial[((size_t)rb*4 + 2)*64 + lane] + partial[((size_t)rb*4 + 3)*64 + lane];
    float s = v;
    for (int off = 32; off >= 1; off >>= 1) s += __shfl_xor(s, off);
    v = v / (s + 1e-8f);
    int k = (r == 0 || r == 4) ? 16 : 8;
    __shared__ float tv[16];
    __shared__ int   tix[16];
    float cur = v;
    for (int it = 0; it < k; ++it) {
        float bv = cur; int bi = lane;
        for (int off = 32; off >= 1; off >>= 1) {
            float ov = __shfl_xor(bv, off);
            int   oi = __shfl_xor(bi, off);
            if (ov > bv || (ov == bv && oi < bi)) { bv = ov; bi = oi; }
        }
        if (bi == lane) cur = -1e30f;
        if (lane == 0) { tv[it] = bv; tix[it] = bi; }
    }
    __syncthreads();
    float s2 = 0.f;
    for (int i = 0; i < k; ++i) s2 += tv[i];
    float inv = 1.f / (s2 + 1e-8f);
    if (lane < k) {
        tw[(size_t)rb*16 + lane] = tv[lane] * inv;
        ti[(size_t)rb*16 + lane] = tix[lane];
    }
}

// ======================================================================
// Fused expert combine: all 5 segments in one launch (blockIdx.z = seg).
// ======================================================================
__global__ __launch_bounds__(256) void combine_all(
    const float* __restrict__ neurons, const float* __restrict__ pool,
    const float* __restrict__ tw, const int* __restrict__ ti,
    ush* __restrict__ hhmBh, ush* __restrict__ hhmBl,
    ush* __restrict__ qkvBh, ush* __restrict__ qkvBl)
{
    int seg = blockIdx.z;
    int b = blockIdx.y;
    const float* table;
    int twIdx, k, nInner, rowStride, colOff;
    ush *outhi, *outlo;
    long long sOut;
    if (seg < 2) {
        table = neurons; k = 16; nInner = 256; rowStride = 512;
        twIdx = (seg == 0) ? 0 : 4;
        colOff = (seg == 0) ? 0 : 256;
        outhi = hhmBh; outlo = hhmBl; sOut = (long long)2*EPE;
    } else {
        table = pool; k = 8; nInner = 1024; rowStride = TDN;
        twIdx = seg - 1;                       // 1,2,3
        colOff = (seg - 2)*1024;               // 0,1024,2048
        outhi = qkvBh; outlo = qkvBl; sOut = (long long)3*EPE;
    }
    const float* twp = tw + (size_t)(twIdx*Bn + b)*16;
    const int*   tip = ti + (size_t)(twIdx*Bn + b)*16;

    size_t e = ((size_t)blockIdx.x*256 + threadIdx.x)*4;
    float4 acc = {0.f, 0.f, 0.f, 0.f};
    for (int i = 0; i < k; ++i) {
        float w = twp[i];
        int  idx = tip[i];
        float4 t = *(const float4*)&table[(size_t)idx*EPE + e];
        acc.x += w*t.x; acc.y += w*t.y; acc.z += w*t.z; acc.w += w*t.w;
    }
    float vals[4] = {acc.x, acc.y, acc.z, acc.w};
    ushort4v h, l;
#pragma unroll
    for (int i = 0; i < 4; ++i) {
        ush a, b2; f2bf_split(vals[i], a, b2);
        h[i] = a; l[i] = b2;
    }
    int row = (int)(e / nInner), col = (int)(e % nInner);
    size_t dst = (size_t)b*sOut + (size_t)row*rowStride + colOff + col;
    *(ushort4v*)&outhi[dst] = h;
    *(ushort4v*)&outlo[dst] = l;
}

// ======================================================================
// MFMA bf16 flash attention, merged dual-q-tile, merged QKV input,
// split-plane output, setprio around MFMA (T5).
// ======================================================================
#define PADK 72

__global__ __launch_bounds__(256, 4) void attn_mfma_kernel(
    const ush* __restrict__ QKV,
    ush* __restrict__ Ohi, ush* __restrict__ Olo)
{
    int aa = blockIdx.x;                // 0..7
    int hh = blockIdx.y, b = blockIdx.z;
    int qt0 = aa, qt1 = 15 - aa;        // qt0 < qt1 always
    int tid  = threadIdx.x;
    int wave = tid >> 6, lane = tid & 63;
    int lr = lane & 15, lg = lane >> 4;

    __shared__ __align__(16) ush Kt[64][PADK];
    __shared__ __align__(16) ush Vt[64][PADK];   // Vt[d][kv]
    __shared__ __align__(16) ush Pt[64][PADK];

    const ush* Qr0 = QKV + ((size_t)b*Sn + (size_t)qt0*64 + wave*16 + lr)*TDN + hh*64;
    const ush* Qr1 = QKV + ((size_t)b*Sn + (size_t)qt1*64 + wave*16 + lr)*TDN + hh*64;
    short8 q0a = *(const short8*)&Qr0[lg*8];
    short8 q0b = *(const short8*)&Qr0[32 + lg*8];
    short8 q1a = *(const short8*)&Qr1[lg*8];
    short8 q1b = *(const short8*)&Qr1[32 + lg*8];

    f32x4 o0[4], o1[4];
    float m0[4], l0[4], m1[4], l1[4];
#pragma unroll
    for (int ct = 0; ct < 4; ++ct) {
        o0[ct] = (f32x4){0.f,0.f,0.f,0.f};
        o1[ct] = (f32x4){0.f,0.f,0.f,0.f};
    }
#pragma unroll
    for (int r = 0; r < 4; ++r) {
        m0[r] = -1e30f; l0[r] = 0.f;
        m1[r] = -1e30f; l1[r] = 0.f;
    }

    auto process = [&](short8 qa, short8 qb, f32x4 (&o)[4],
                       float (&m)[4], float (&l)[4], int qt, int kt) {
        f32x4 s[4];
        __builtin_amdgcn_s_setprio(1);
#pragma unroll
        for (int ct = 0; ct < 4; ++ct) {
            s[ct] = (f32x4){0.f,0.f,0.f,0.f};
            short8 k0 = *(const short8*)&Kt[ct*16 + lr][lg*8];
            short8 k1 = *(const short8*)&Kt[ct*16 + lr][32 + lg*8];
            s[ct] = __builtin_amdgcn_mfma_f32_16x16x32_bf16(qa, k0, s[ct], 0, 0, 0);
            s[ct] = __builtin_amdgcn_mfma_f32_16x16x32_bf16(qb, k1, s[ct], 0, 0, 0);
        }
        __builtin_amdgcn_s_setprio(0);
        float mx[4] = {-1e30f,-1e30f,-1e30f,-1e30f};
        int qg0 = qt*64 + wave*16 + lg*4;
#pragma unroll
        for (int ct = 0; ct < 4; ++ct) {
            int kvg = kt*64 + ct*16 + lr;
#pragma unroll
            for (int r = 0; r < 4; ++r) {
                float v = s[ct][r] * 0.125f;
                if (kt == qt && kvg > qg0 + r) v = -1e30f;
                s[ct][r] = v;
                mx[r] = fmaxf(mx[r], v);
            }
        }
#pragma unroll
        for (int r = 0; r < 4; ++r) {
            mx[r] = fmaxf(mx[r], __shfl_xor(mx[r], 1));
            mx[r] = fmaxf(mx[r], __shfl_xor(mx[r], 2));
            mx[r] = fmaxf(mx[r], __shfl_xor(mx[r], 4));
            mx[r] = fmaxf(mx[r], __shfl_xor(mx[r], 8));
        }
        float corr[4], ps[4] = {0.f,0.f,0.f,0.f};
#pragma unroll
        for (int r = 0; r < 4; ++r) {
            float mn = fmaxf(m[r], mx[r]);
            corr[r] = __expf(m[r] - mn);
            m[r] = mn;
        }
#pragma unroll
        for (int ct = 0; ct < 4; ++ct)
#pragma unroll
            for (int r = 0; r < 4; ++r) {
                float e = __expf(s[ct][r] - m[r]);
                s[ct][r] = e;
                ps[r] += e;
            }
#pragma unroll
        for (int r = 0; r < 4; ++r) {
            ps[r] += __shfl_xor(ps[r], 1);
            ps[r] += __shfl_xor(ps[r], 2);
            ps[r] += __shfl_xor(ps[r], 4);
            ps[r] += __shfl_xor(ps[r], 8);
            l[r] = l[r]*corr[r] + ps[r];
#pragma unroll
            for (int ct = 0; ct < 4; ++ct) o[ct][r] *= corr[r];
        }
#pragma unroll
        for (int ct = 0; ct < 4; ++ct)
#pragma unroll
            for (int r = 0; r < 4; ++r)
                Pt[wave*16 + lg*4 + r][ct*16 + lr] = f2bf(s[ct][r]);
        short8 pa0 = *(const short8*)&Pt[wave*16 + lr][lg*8];
        short8 pa1 = *(const short8*)&Pt[wave*16 + lr][32 + lg*8];
        __builtin_amdgcn_s_setprio(1);
#pragma unroll
        for (int ct = 0; ct < 4; ++ct) {
            short8 v0 = *(const short8*)&Vt[ct*16 + lr][lg*8];
            short8 v1 = *(const short8*)&Vt[ct*16 + lr][32 + lg*8];
            o[ct] = __builtin_amdgcn_mfma_f32_16x16x32_bf16(pa0, v0, o[ct], 0, 0, 0);
            o[ct] = __builtin_amdgcn_mfma_f32_16x16x32_bf16(pa1, v1, o[ct], 0, 0, 0);
        }
        __builtin_amdgcn_s_setprio(0);
    };

    for (int kt = 0; kt <= qt1; ++kt) {
        __syncthreads();
        const ush* Kb = QKV + ((size_t)b*Sn + (size_t)kt*64)*TDN + 1024 + hh*64;
        const ush* Vb = QKV + ((size_t)b*Sn + (size_t)kt*64)*TDN + 2048 + hh*64;
#pragma unroll
        for (int it2 = 0; it2 < 2; ++it2) {
            int idx = tid + it2*256;
            int kv = idx >> 3, d0 = (idx & 7)*8;
            *(short8*)&Kt[kv][d0] = *(const short8*)&Kb[(size_t)kv*TDN + d0];
        }
#pragma unroll
        for (int it2 = 0; it2 < 2; ++it2) {
            int idx = tid + it2*256;
            int kv = idx & 63, d0 = (idx >> 6)*8;
            short8 w = *(const short8*)&Vb[(size_t)kv*TDN + d0];
#pragma unroll
            for (int e = 0; e < 8; ++e) Vt[d0+e][kv] = (ush)w[e];
        }
        __syncthreads();

        if (kt <= qt0) process(q0a, q0b, o0, m0, l0, qt0, kt);
        process(q1a, q1b, o1, m1, l1, qt1, kt);
    }

    {
        size_t base = ((size_t)b*Sn + (size_t)qt0*64 + wave*16 + lg*4)*Dn + hh*64 + lr;
#pragma unroll
        for (int r = 0; r < 4; ++r) {
            float inv = 1.f / l0[r];
#pragma unroll
            for (int ct = 0; ct < 4; ++ct) {
                float val = o0[ct][r] * inv;
                ush h, lo2; f2bf_split(val, h, lo2);
                Ohi[base + (size_t)r*Dn + ct*16] = h;
                Olo[base + (size_t)r*Dn + ct*16] = lo2;
            }
        }
    }
    {
        size_t base = ((size_t)b*Sn + (size_t)qt1*64 + wave*16 + lg*4)*Dn + hh*64 + lr;
#pragma unroll
        for (int r = 0; r < 4; ++r) {
            float inv = 1.f / l1[r];
#pragma unroll
            for (int ct = 0; ct < 4; ++ct) {
                float val = o1[ct][r] * inv;
                ush h, lo2; f2bf_split(val, h, lo2);
                Ohi[base + (size_t)r*Dn + ct*16] = h;
                Olo[base + (size_t)r*Dn + ct*16] = lo2;
            }
        }
    }
}

// ======================================================================
// Knowledge memory, wave-per-token, bf16 scores (8192 tokens).
// COALESCED ownership: lane owns elements {j8*512 + lane*8 + e} so each
// short8 load is 64 lanes x 16B = 1KB contiguous. Selection semantics
// are partition-independent (threshold bound + global-index ordering).
// ======================================================================
__global__ __launch_bounds__(256) void mem_topk_wave(
    const ush* __restrict__ ksc,     // [8192][4096] bf16 scores
    const float* __restrict__ hm,    // [8192][256] f32
    const float* __restrict__ kK,    // [4096][256]
    const float* __restrict__ kV,    // [4096][1024]
    float* __restrict__ out)
{
    int wave = threadIdx.x >> 6, lane = threadIdx.x & 63;
    int t = blockIdx.x*4 + wave;            // global token 0..8191
    const ush* row = ksc + (size_t)t*NKn;

    float v[64];
    float lmax = -3e38f;
#pragma unroll
    for (int j8 = 0; j8 < 8; ++j8) {
        short8 w = *(const short8*)&row[j8*512 + lane*8];   // coalesced 1KB/wave
#pragma unroll
        for (int e = 0; e < 8; ++e) {
            float f = bf2f((ush)w[e]);
            v[j8*8+e] = f;
            lmax = fmaxf(lmax, f);
        }
    }
    // global index of register element j:
    //   GIDX(j) = (j>>3)*512 + lane*8 + (j&7)

    float sv = lmax;
#pragma unroll
    for (int k = 2; k <= 64; k <<= 1) {
#pragma unroll
        for (int j = k >> 1; j >= 1; j >>= 1) {
            float ov = __shfl_xor(sv, j);
            bool keepLarger = (((lane & j) == 0) == ((lane & k) == 0));
            float mx = fmaxf(sv, ov), mn = fminf(sv, ov);
            sv = keepLarger ? mx : mn;
        }
    }
    float T = __shfl(sv, 15);   // 16th largest lane max (valid bound for any partition)

    __shared__ float s_cv[4][64];
    __shared__ int   s_cix[4][64];
    __shared__ float s_cs[4][16];
    __shared__ int   s_tix[4][16];

    int cnt = 0;
#pragma unroll
    for (int j = 0; j < 64; ++j) cnt += (v[j] >= T) ? 1 : 0;
    int pre = cnt;
#pragma unroll
    for (int off2 = 1; off2 < 64; off2 <<= 1) {
        int og = __shfl_up(pre, off2);
        if (lane >= off2) pre += og;
    }
    int C = __shfl(pre, 63);
    int base = pre - cnt;

    if (C <= 64) {
        int pos = base;
#pragma unroll
        for (int j = 0; j < 64; ++j) {
            if (v[j] >= T) {
                s_cv[wave][pos] = v[j];
                s_cix[wave][pos] = (j >> 3)*512 + lane*8 + (j & 7);
                ++pos;
            }
        }
        float cv2 = (lane < C) ? s_cv[wave][lane] : -3e38f;
        int   cix = (lane < C) ? s_cix[wave][lane] : 0x7fffffff;
#pragma unroll
        for (int k = 2; k <= 64; k <<= 1) {
#pragma unroll
            for (int j = k >> 1; j >= 1; j >>= 1) {
                float ov = __shfl_xor(cv2, j);
                int   oi = __shfl_xor(cix, j);
                bool amLarger = (cv2 > ov) || (cv2 == ov && cix < oi);
                bool keepLarger = (((lane & j) == 0) == ((lane & k) == 0));
                if (amLarger != keepLarger) { cv2 = ov; cix = oi; }
            }
        }
        if (lane < 16) s_tix[wave][lane] = cix;
    } else {
        for (int it = 0; it < 16; ++it) {
            float bv = -3e38f; int bi = 0x7fffffff;
#pragma unroll
            for (int j = 0; j < 64; ++j) {
                int n = (j >> 3)*512 + lane*8 + (j & 7);
                if (v[j] > bv || (v[j] == bv && n < bi)) { bv = v[j]; bi = n; }
            }
#pragma unroll
            for (int off2 = 32; off2 >= 1; off2 >>= 1) {
                float ov = __shfl_xor(bv, off2);
                int   oi = __shfl_xor(bi, off2);
                if (ov > bv || (ov == bv && oi < bi)) { bv = ov; bi = oi; }
            }
            if (lane == 0) s_tix[wave][it] = bi;
#pragma unroll
            for (int j = 0; j < 64; ++j)
                if ((j >> 3)*512 + lane*8 + (j & 7) == bi) v[j] = -3e38f;
        }
    }

    int c = lane >> 2, q = lane & 3;
    int kidx = s_tix[wave][c];
    const float* kr = kK + (size_t)kidx*Rn;
    const float* hr = hm + (size_t)t*Rn;
    float d = 0.f;
#pragma unroll
    for (int j4 = 0; j4 < 16; ++j4) {
        float4 a  = *(const float4*)&hr[q*64 + j4*4];
        float4 bb = *(const float4*)&kr[q*64 + j4*4];
        d += a.x*bb.x + a.y*bb.y + a.z*bb.z + a.w*bb.w;
    }
    d += __shfl_xor(d, 1);
    d += __shfl_xor(d, 2);
    if (q == 0) s_cs[wave][c] = d * 0.0625f;      // 1/sqrt(256)

    float cv = (lane < 16) ? s_cs[wave][lane] : -3e38f;
    int   ck = (lane < 16) ? s_tix[wave][lane] : 0x7fffffff;
    float sv8[8]; int si[8];
#pragma unroll
    for (int it = 0; it < 8; ++it) {
        float bv = cv; int bk = ck;
#pragma unroll
        for (int off2 = 32; off2 >= 1; off2 >>= 1) {
            float ov = __shfl_xor(bv, off2);
            int   ok = __shfl_xor(bk, off2);
            if (ov > bv || (ov == bv && ok < bk)) { bv = ov; bk = ok; }
        }
        sv8[it] = bv; si[it] = bk;
        if (ck == bk) cv = -3e38f;
    }

    float mxv = sv8[0];
#pragma unroll
    for (int kx = 1; kx < 8; ++kx) mxv = fmaxf(mxv, sv8[kx]);
    float p[8]; float sum = 0.f;
#pragma unroll
    for (int kx = 0; kx < 8; ++kx) { p[kx] = __expf(sv8[kx] - mxv); sum += p[kx]; }
    float invs = 1.f / sum;
    float4 acc0 = {0,0,0,0}, acc1 = {0,0,0,0}, acc2 = {0,0,0,0}, acc3 = {0,0,0,0};
#pragma unroll
    for (int kx = 0; kx < 8; ++kx) {
        float pk = p[kx]*invs;
        const float* vp = kV + (size_t)si[kx]*Dn + lane*16;
        float4 v0 = *(const float4*)(vp + 0);
        float4 v1 = *(const float4*)(vp + 4);
        float4 v2 = *(const float4*)(vp + 8);
        float4 v3 = *(const float4*)(vp + 12);
        acc0.x += pk*v0.x; acc0.y += pk*v0.y; acc0.z += pk*v0.z; acc0.w += pk*v0.w;
        acc1.x += pk*v1.x; acc1.y += pk*v1.y; acc1.z += pk*v1.z; acc1.w += pk*v1.w;
        acc2.x += pk*v2.x; acc2.y += pk*v2.y; acc2.z += pk*v2.z; acc2.w += pk*v2.w;
        acc3.x += pk*v3.x; acc3.y += pk*v3.y; acc3.z += pk*v3.z; acc3.w += pk*v3.w;
    }
    float* op = out + (size_t)t*Dn + lane*16;
    float4 c0 = *(const float4*)(op + 0);
    float4 c1 = *(const float4*)(op + 4);
    float4 c2 = *(const float4*)(op + 8);
    float4 c3 = *(const float4*)(op + 12);
    c0.x+=acc0.x; c0.y+=acc0.y; c0.z+=acc0.z; c0.w+=acc0.w;
    c1.x+=acc1.x; c1.y+=acc1.y; c1.z+=acc1.z; c1.w+=acc1.w;
    c2.x+=acc2.x; c2.y+=acc2.y; c2.z+=acc2.z; c2.w+=acc2.w;
    c3.x+=acc3.x; c3.y+=acc3.y; c3.z+=acc3.z; c3.w+=acc3.w;
    *(float4*)(op + 0)  = c0;
    *(float4*)(op + 4)  = c1;
    *(float4*)(op + 8)  = c2;
    *(float4*)(op + 12) = c3;
}

// ======================================================================
extern "C" void kernel_launch(void* const* d_in, const int* in_sizes, int n_in,
                              void* d_out, int out_size, void* d_ws, size_t ws_size,
                              hipStream_t stream)
{
    const float* x          = (const float*)d_in[0];
    const float* imp        = (const float*)d_in[1];
    const float* compress_w = (const float*)d_in[2];
    const float* expQ_w     = (const float*)d_in[3];
    const float* expK_w     = (const float*)d_in[4];
    const float* expV_w     = (const float*)d_in[5];
    const float* memory_w   = (const float*)d_in[6];
    const float* neurons    = (const float*)d_in[7];   // [64, D, R]
    const float* pool       = (const float*)d_in[8];   // [64, R, D]
    const float* kK         = (const float*)d_in[9];   // [4096, R]
    const float* kV         = (const float*)d_in[10];  // [4096, D]
    const float* Wo         = (const float*)d_in[11];  // [D, D]
    float* out = (float*)d_out;

    // ---- workspace layout (~195 MB) ----
    char* ws = (char*)d_ws;
    size_t off = 0;
    auto alloc = [&](size_t bytes) {
        size_t o = off; off = (off + bytes + 255) & ~(size_t)255; return (void*)(ws + o);
    };
    ush* xqh    = (ush*)alloc((size_t)TOK*Dn*2);
    ush* xql    = (ush*)alloc((size_t)TOK*Dn*2);
    ush* wcatqh = (ush*)alloc((size_t)320*Dn*2);
    ush* wcatql = (ush*)alloc((size_t)320*Dn*2);
    ush* Woqh   = (ush*)alloc((size_t)Dn*Dn*2);
    ush* Woql   = (ush*)alloc((size_t)Dn*Dn*2);
    ush* kKqh   = (ush*)alloc((size_t)NKn*Rn*2);
    ush* kKql   = (ush*)alloc((size_t)NKn*Rn*2);
    float* logits  = (float*)alloc((size_t)TOK*320*4);
    float* partial = (float*)alloc((size_t)40*4*64*4);
    float* tw      = (float*)alloc((size_t)5*Bn*16*4);
    int*   ti      = (int*)  alloc((size_t)5*Bn*16*4);
    ush* hhmBh = (ush*)alloc((size_t)Bn*2*EPE*2);   // [b][1024][512] K x (h|hm)
    ush* hhmBl = (ush*)alloc((size_t)Bn*2*EPE*2);
    ush* qkvBh = (ush*)alloc((size_t)Bn*3*EPE*2);   // [b][256][3072] K x (Q|K|V)
    ush* qkvBl = (ush*)alloc((size_t)Bn*3*EPE*2);
    ush* hqh   = (ush*)alloc((size_t)TOK*Rn*2);
    ush* hql   = (ush*)alloc((size_t)TOK*Rn*2);
    float* hm  = (float*)alloc((size_t)TOK*Rn*4);
    ush* hmqh  = (ush*)alloc((size_t)TOK*Rn*2);
    ush* QKVb  = (ush*)alloc((size_t)TOK*TDN*2);    // 48 MB
    ush* Obqh  = (ush*)alloc((size_t)TOK*Dn*2);     // 16 MB
    ush* Obql  = (ush*)alloc((size_t)TOK*Dn*2);     // 16 MB
    // ksc bf16 [8192][4096] = 64MB aliases QKVb+Obqh (dead after Wo GEMM)
    ush* ksc = QKVb;
    (void)ws_size; (void)in_sizes; (void)n_in; (void)out_size;

    // ---- 0. pre-split conversions (2 launches) ----
    convert3<<<10240, 256, 0, stream>>>(
        x, xqh, xql, (long long)TOK*Dn/4,
        Wo, Woqh, Woql, (long long)Dn*Dn/4,
        kK, kKqh, kKql, (long long)NKn*Rn/4);
    convert_w5<<<dim3(64, 5), 256, 0, stream>>>(
        compress_w, expQ_w, expK_w, expV_w, memory_w, wcatqh, wcatql);

    // ---- 1. routers: 64-tile GEMM (640 blocks), fused post, topk ----
    gemm64<<<dim3(5, 128, 1), 256, 0, stream>>>(
        xqh, xql, wcatqh, wcatql, logits, nullptr, nullptr, nullptr,
        320, Dn, 0LL, 0LL, 0LL, 0LL, 1.f, 0 /*NK*/, 3, 0);
    router_post<<<160, 256, 0, stream>>>(logits, imp, partial);
    topk_router<<<40, 64, 0, stream>>>(partial, tw, ti);

    // ---- 2. fused expert combines (one launch, 5 segments) ----
    combine_all<<<dim3(EPE/1024, Bn, 5), 256, 0, stream>>>(
        neurons, pool, tw, ti, hhmBh, hhmBl, qkvBh, qkvBl);

    // ---- 3. h+hm merged (N=512, 64-tile, 1024 blocks) ----
    gemm64<<<dim3(8, 16, Bn), 256, 0, stream>>>(
        xqh, xql, hhmBh, hhmBl, hqh, hql, hm, hmqh,
        512, Dn, (long long)Sn*Dn, (long long)2*EPE,
        (long long)Sn*Rn, (long long)Sn*Rn, 1.f, 1 /*KN*/, 3, 1);

    // ---- 4. merged QKV (N=3072, 128-tile, 3072 blocks, bf16 out) ----
    gemm_pre<<<dim3(TDN/64, Sn/128, Bn), 256, 0, stream>>>(
        hqh, hql, qkvBh, qkvBl, QKVb, nullptr,
        Sn, TDN, Rn, (long long)Sn*Rn, (long long)3*EPE, (long long)Sn*TDN,
        1.f, 1 /*KN*/, 3, 1, 0);

    // ---- 5. causal flash attention (merged QKV in, split-plane out) ----
    attn_mfma_kernel<<<dim3(8, NHn, Bn), 256, 0, stream>>>(QKVb, Obqh, Obql);

    // ---- 6. output projection: d_out = O @ Wo^T (2 passes, gridSwap) ----
    gemm_pre<<<dim3(TOK/128, Dn/64, 1), 256, 0, stream>>>(
        Obqh, Obql, Woqh, Woql, out, nullptr,
        TOK, Dn, Dn, 0LL, 0LL, 0LL, 1.f, 0 /*NK*/, 2, 0, 1 /*gridSwap*/);

    // ---- 7. knowledge memory: one GEMM (M=8192) + one topk launch ----
    gemm_pre<<<dim3(NKn/64, TOK/128, 1), 256, 0, stream>>>(
        hmqh, nullptr, kKqh, nullptr, ksc, nullptr,
        TOK, NKn, Rn, 0LL, 0LL, 0LL, 0.0625f, 0 /*NK*/, 1, 1 /*bf16*/, 0);
    mem_topk_wave<<<2048, 256, 0, stream>>>(ksc, hm, kK, kV, out);
}

// Round 16
// 600.488 us; speedup vs baseline: 1.0094x; 1.0094x over previous
//
#include <hip/hip_runtime.h>

// Problem constants
#define Bn   8
#define Sn   1024
#define Dn   1024
#define Rn   256
#define NHn  16
#define DHn  64
#define NKn  4096
#define TOK  (Bn*Sn)        // 8192 tokens
#define EPE  (Dn*Rn)        // 262144 elements per expert table entry
#define TDN  3072           // merged QKV row stride
#define BPAD 44             // Bs row stride (22 dwords; 8-row group == 16 mod 32)

typedef __attribute__((ext_vector_type(8))) short short8;   // 8 bf16 (4 VGPR)
typedef __attribute__((ext_vector_type(4))) short short4v;  // 8B
typedef __attribute__((ext_vector_type(4))) float f32x4;
typedef __attribute__((ext_vector_type(4))) unsigned short ushort4v;
typedef unsigned short ush;

__device__ inline ush f2bf(float f) {
    union { float f; unsigned u; } v; v.f = f;
    unsigned r = v.u + 0x7fffu + ((v.u >> 16) & 1u);   // round-to-nearest-even
    return (ush)(r >> 16);
}
__device__ inline float bf2f(ush h) {
    union { unsigned u; float f; } v; v.u = ((unsigned)h) << 16;
    return v.f;
}
__device__ inline void f2bf_split(float f, ush& hi, ush& lo) {
    hi = f2bf(f);
    lo = f2bf(f - bf2f(hi));
}
__device__ inline short8 cat8(short4v a, short4v b) {
    short8 r;
    r[0]=a[0]; r[1]=a[1]; r[2]=a[2]; r[3]=a[3];
    r[4]=b[0]; r[5]=b[1]; r[6]=b[2]; r[7]=b[3];
    return r;
}

// ======================================================================
// Fused conversions: three tensors in one launch (x, Wo, kK).
// ======================================================================
__global__ __launch_bounds__(256) void convert3(
    const float* __restrict__ s0, ush* __restrict__ h0, ush* __restrict__ l0, long long n40,
    const float* __restrict__ s1, ush* __restrict__ h1, ush* __restrict__ l1, long long n41,
    const float* __restrict__ s2, ush* __restrict__ h2, ush* __restrict__ l2, long long n42)
{
    long long i = (long long)blockIdx.x*256 + threadIdx.x;
    const float* s; ush* h; ush* l;
    if (i < n40) { s = s0; h = h0; l = l0; }
    else if (i < n40 + n41) { i -= n40; s = s1; h = h1; l = l1; }
    else { i -= n40 + n41; if (i >= n42) return; s = s2; h = h2; l = l2; }
    float4 f = *(const float4*)&s[i*4];
    float vals[4] = {f.x, f.y, f.z, f.w};
    ushort4v hv, lv;
#pragma unroll
    for (int e = 0; e < 4; ++e) { ush a, b2; f2bf_split(vals[e], a, b2); hv[e] = a; lv[e] = b2; }
    *(ushort4v*)&h[i*4] = hv;
    *(ushort4v*)&l[i*4] = lv;
}

// 5 router weight matrices (each 64x1024) -> concat planes. grid (64,5).
__global__ __launch_bounds__(256) void convert_w5(
    const float* __restrict__ w0, const float* __restrict__ w1,
    const float* __restrict__ w2, const float* __restrict__ w3,
    const float* __restrict__ w4, ush* __restrict__ hi, ush* __restrict__ lo)
{
    int y = blockIdx.y;
    const float* srcs[5] = {w0, w1, w2, w3, w4};
    const float* s = srcs[y];
    long long i = (long long)blockIdx.x*256 + threadIdx.x;   // < 16384
    float4 f = *(const float4*)&s[i*4];
    float vals[4] = {f.x, f.y, f.z, f.w};
    ushort4v hv, lv;
#pragma unroll
    for (int e = 0; e < 4; ++e) { ush a, b2; f2bf_split(vals[e], a, b2); hv[e] = a; lv[e] = b2; }
    size_t dst = (size_t)y*64*Dn + i*4;
    *(ushort4v*)&hi[dst] = hv;
    *(ushort4v*)&lo[dst] = lv;
}

// ======================================================================
// Pre-split bf16 MFMA GEMM, tile 128x64 (BK=32), 4 waves (2x2).
// Bs stride BPAD=44 (conflict-fixed); all Bs traffic via b64 pairs.
// outMode: 0 f32->C0; 1 bf16->C0; 2 hi->C0,lo->C1.
// gridSwap: 0 -> (x=col,y=row); 1 -> (x=row,y=col)  [A-L2/XCD locality]
// ======================================================================
__global__ __launch_bounds__(256) void gemm_pre(
    const ush* __restrict__ Ahi, const ush* __restrict__ Alo,
    const ush* __restrict__ Bhi, const ush* __restrict__ Blo,
    void* __restrict__ C0, void* __restrict__ C1,
    int M, int N, int K, long long sA, long long sB, long long sC,
    float alpha, int bTrans, int passes, int outMode, int gridSwap)
{
    Ahi += (size_t)blockIdx.z * sA;
    if (Alo) Alo += (size_t)blockIdx.z * sA;
    Bhi += (size_t)blockIdx.z * sB;
    if (Blo) Blo += (size_t)blockIdx.z * sB;
    __shared__ __align__(16) ush AsH[128][40];
    __shared__ __align__(16) ush AsL[128][40];
    __shared__ __align__(16) ush BsH[64][BPAD];
    __shared__ __align__(16) ush BsL[64][BPAD];
    int tid = threadIdx.x;
    int wave = tid >> 6, lane = tid & 63;
    int lr = lane & 15, lg = lane >> 4;
    int wm = (wave >> 1)*64, wn = (wave & 1)*32;
    int row0 = (gridSwap ? blockIdx.x : blockIdx.y)*128;
    int col0 = (gridSwap ? blockIdx.y : blockIdx.x)*64;

    f32x4 acc[4][2];
#pragma unroll
    for (int i = 0; i < 4; ++i)
#pragma unroll
        for (int j = 0; j < 2; ++j) acc[i][j] = (f32x4){0.f,0.f,0.f,0.f};

    for (int k0 = 0; k0 < K; k0 += 32) {
        __syncthreads();
#pragma unroll
        for (int g = 0; g < 2; ++g) {
            int idx = tid + g*256;
            int m2 = idx >> 2, kk = (idx & 3)*8;
            size_t so = (size_t)(row0 + m2)*K + k0 + kk;
            *(short8*)&AsH[m2][kk] = *(const short8*)&Ahi[so];
            if (passes >= 2) *(short8*)&AsL[m2][kk] = *(const short8*)&Alo[so];
        }
        if (!bTrans) {                       // B is [N][K]: copy via b64 pairs
            int n2 = tid >> 2, kk = (tid & 3)*8;
            size_t so = (size_t)(col0 + n2)*K + k0 + kk;
            *(short4v*)&BsH[n2][kk]     = *(const short4v*)&Bhi[so];
            *(short4v*)&BsH[n2][kk + 4] = *(const short4v*)&Bhi[so + 4];
            if (passes >= 3) {
                *(short4v*)&BsL[n2][kk]     = *(const short4v*)&Blo[so];
                *(short4v*)&BsL[n2][kk + 4] = *(const short4v*)&Blo[so + 4];
            }
        } else {                             // B is [K][N]: transpose copy
            int kk = tid >> 3, n0 = (tid & 7)*8;
            size_t so = (size_t)(k0 + kk)*N + col0 + n0;
            short8 wh = *(const short8*)&Bhi[so];
#pragma unroll
            for (int e = 0; e < 8; ++e) BsH[n0+e][kk] = (ush)wh[e];
            if (passes >= 3) {
                short8 wl = *(const short8*)&Blo[so];
#pragma unroll
                for (int e = 0; e < 8; ++e) BsL[n0+e][kk] = (ush)wl[e];
            }
        }
        __syncthreads();
        short8 afH[4], bfH[2];
#pragma unroll
        for (int i = 0; i < 4; ++i) afH[i] = *(const short8*)&AsH[wm + i*16 + lr][lg*8];
#pragma unroll
        for (int j = 0; j < 2; ++j)
            bfH[j] = cat8(*(const short4v*)&BsH[wn + j*16 + lr][lg*8],
                          *(const short4v*)&BsH[wn + j*16 + lr][lg*8 + 4]);
#pragma unroll
        for (int i = 0; i < 4; ++i)
#pragma unroll
            for (int j = 0; j < 2; ++j)
                acc[i][j] = __builtin_amdgcn_mfma_f32_16x16x32_bf16(afH[i], bfH[j], acc[i][j], 0, 0, 0);
        if (passes >= 2) {
            short8 afL[4];
#pragma unroll
            for (int i = 0; i < 4; ++i) afL[i] = *(const short8*)&AsL[wm + i*16 + lr][lg*8];
#pragma unroll
            for (int i = 0; i < 4; ++i)
#pragma unroll
                for (int j = 0; j < 2; ++j)
                    acc[i][j] = __builtin_amdgcn_mfma_f32_16x16x32_bf16(afL[i], bfH[j], acc[i][j], 0, 0, 0);
        }
        if (passes >= 3) {
            short8 bfL[2];
#pragma unroll
            for (int j = 0; j < 2; ++j)
                bfL[j] = cat8(*(const short4v*)&BsL[wn + j*16 + lr][lg*8],
                              *(const short4v*)&BsL[wn + j*16 + lr][lg*8 + 4]);
#pragma unroll
            for (int i = 0; i < 4; ++i)
#pragma unroll
                for (int j = 0; j < 2; ++j)
                    acc[i][j] = __builtin_amdgcn_mfma_f32_16x16x32_bf16(afH[i], bfL[j], acc[i][j], 0, 0, 0);
        }
    }
#pragma unroll
    for (int i = 0; i < 4; ++i)
#pragma unroll
        for (int j = 0; j < 2; ++j)
#pragma unroll
            for (int r = 0; r < 4; ++r) {
                size_t eo = (size_t)(row0 + wm + i*16 + lg*4 + r)*N + col0 + wn + j*16 + lr;
                float val = acc[i][j][r] * alpha;
                if (outMode == 0) {
                    ((float*)C0 + (size_t)blockIdx.z*sC)[eo] = val;
                } else if (outMode == 1) {
                    ((ush*)C0 + (size_t)blockIdx.z*sC)[eo] = f2bf(val);
                } else {
                    ush h, l; f2bf_split(val, h, l);
                    ((ush*)C0 + (size_t)blockIdx.z*sC)[eo] = h;
                    ((ush*)C1 + (size_t)blockIdx.z*sC)[eo] = l;
                }
            }
}

// ======================================================================
// 64x64-tile GEMM (4 waves of 32x32), Bs stride BPAD, b64 B-traffic.
// mode 0: f32 -> C0 (width N). mode 1 (h+hm): cols<N/2 -> split planes
// C0/C1 (width N/2); cols>=N/2 -> f32 C2 + hi C3 (width N/2).
// ======================================================================
__global__ __launch_bounds__(256) void gemm64(
    const ush* __restrict__ Ahi, const ush* __restrict__ Alo,
    const ush* __restrict__ Bhi, const ush* __restrict__ Blo,
    void* __restrict__ C0, void* __restrict__ C1,
    void* __restrict__ C2, void* __restrict__ C3,
    int N, int K, long long sA, long long sB, long long sCL, long long sCR,
    float alpha, int bTrans, int passes, int mode)
{
    Ahi += (size_t)blockIdx.z * sA;
    if (Alo) Alo += (size_t)blockIdx.z * sA;
    Bhi += (size_t)blockIdx.z * sB;
    if (Blo) Blo += (size_t)blockIdx.z * sB;
    __shared__ __align__(16) ush AsH[64][40];
    __shared__ __align__(16) ush AsL[64][40];
    __shared__ __align__(16) ush BsH[64][BPAD];
    __shared__ __align__(16) ush BsL[64][BPAD];
    int tid = threadIdx.x;
    int wave = tid >> 6, lane = tid & 63;
    int lr = lane & 15, lg = lane >> 4;
    int wm = (wave >> 1)*32, wn = (wave & 1)*32;
    int row0 = blockIdx.y*64, col0 = blockIdx.x*64;

    f32x4 acc[2][2];
#pragma unroll
    for (int i = 0; i < 2; ++i)
#pragma unroll
        for (int j = 0; j < 2; ++j) acc[i][j] = (f32x4){0.f,0.f,0.f,0.f};

    for (int k0 = 0; k0 < K; k0 += 32) {
        __syncthreads();
        {   // stage A 64x32: one short8 per thread
            int m2 = tid >> 2, kk = (tid & 3)*8;
            size_t so = (size_t)(row0 + m2)*K + k0 + kk;
            *(short8*)&AsH[m2][kk] = *(const short8*)&Ahi[so];
            if (passes >= 2) *(short8*)&AsL[m2][kk] = *(const short8*)&Alo[so];
        }
        if (!bTrans) {
            int n2 = tid >> 2, kk = (tid & 3)*8;
            size_t so = (size_t)(col0 + n2)*K + k0 + kk;
            *(short4v*)&BsH[n2][kk]     = *(const short4v*)&Bhi[so];
            *(short4v*)&BsH[n2][kk + 4] = *(const short4v*)&Bhi[so + 4];
            if (passes >= 3) {
                *(short4v*)&BsL[n2][kk]     = *(const short4v*)&Blo[so];
                *(short4v*)&BsL[n2][kk + 4] = *(const short4v*)&Blo[so + 4];
            }
        } else {
            int kk = tid >> 3, n0 = (tid & 7)*8;
            size_t so = (size_t)(k0 + kk)*N + col0 + n0;
            short8 wh = *(const short8*)&Bhi[so];
#pragma unroll
            for (int e = 0; e < 8; ++e) BsH[n0+e][kk] = (ush)wh[e];
            if (passes >= 3) {
                short8 wl = *(const short8*)&Blo[so];
#pragma unroll
                for (int e = 0; e < 8; ++e) BsL[n0+e][kk] = (ush)wl[e];
            }
        }
        __syncthreads();
        short8 afH[2], bfH[2];
#pragma unroll
        for (int i = 0; i < 2; ++i) afH[i] = *(const short8*)&AsH[wm + i*16 + lr][lg*8];
#pragma unroll
        for (int j = 0; j < 2; ++j)
            bfH[j] = cat8(*(const short4v*)&BsH[wn + j*16 + lr][lg*8],
                          *(const short4v*)&BsH[wn + j*16 + lr][lg*8 + 4]);
#pragma unroll
        for (int i = 0; i < 2; ++i)
#pragma unroll
            for (int j = 0; j < 2; ++j)
                acc[i][j] = __builtin_amdgcn_mfma_f32_16x16x32_bf16(afH[i], bfH[j], acc[i][j], 0, 0, 0);
        if (passes >= 2) {
            short8 afL[2];
#pragma unroll
            for (int i = 0; i < 2; ++i) afL[i] = *(const short8*)&AsL[wm + i*16 + lr][lg*8];
#pragma unroll
            for (int i = 0; i < 2; ++i)
#pragma unroll
                for (int j = 0; j < 2; ++j)
                    acc[i][j] = __builtin_amdgcn_mfma_f32_16x16x32_bf16(afL[i], bfH[j], acc[i][j], 0, 0, 0);
        }
        if (passes >= 3) {
            short8 bfL[2];
#pragma unroll
            for (int j = 0; j < 2; ++j)
                bfL[j] = cat8(*(const short4v*)&BsL[wn + j*16 + lr][lg*8],
                              *(const short4v*)&BsL[wn + j*16 + lr][lg*8 + 4]);
#pragma unroll
            for (int i = 0; i < 2; ++i)
#pragma unroll
                for (int j = 0; j < 2; ++j)
                    acc[i][j] = __builtin_amdgcn_mfma_f32_16x16x32_bf16(afH[i], bfL[j], acc[i][j], 0, 0, 0);
        }
    }
    int Nh = N >> 1;
#pragma unroll
    for (int i = 0; i < 2; ++i)
#pragma unroll
        for (int j = 0; j < 2; ++j)
#pragma unroll
            for (int r = 0; r < 4; ++r) {
                int grow = row0 + wm + i*16 + lg*4 + r;
                int gcol = col0 + wn + j*16 + lr;
                float val = acc[i][j][r] * alpha;
                if (mode == 0) {
                    ((float*)C0 + (size_t)blockIdx.z*sCL)[(size_t)grow*N + gcol] = val;
                } else {
                    if (gcol < Nh) {
                        ush h, l; f2bf_split(val, h, l);
                        size_t eo = (size_t)blockIdx.z*sCL + (size_t)grow*Nh + gcol;
                        ((ush*)C0)[eo] = h;
                        ((ush*)C1)[eo] = l;
                    } else {
                        size_t eo = (size_t)blockIdx.z*sCR + (size_t)grow*Nh + (gcol - Nh);
                        ((float*)C2)[eo] = val;
                        ((ush*)C3)[eo] = f2bf(val);
                    }
                }
            }
}

// ======================================================================
// Router post: softmax(logits)*importance, partial-sum over 256-token
// chunks. logits [8192][320]; partial [5][8][4][64].
// ======================================================================
__global__ __launch_bounds__(256) void router_post(
    const float* __restrict__ logits, const float* __restrict__ imp,
    float* __restrict__ partial)
{
    int blk = blockIdx.x;                 // 0..159
    int chunk = blk & 3, b = (blk >> 2) & 7, r = blk >> 5;
    int tid = threadIdx.x, lane = tid & 63, wv = tid >> 6;
    float acc = 0.f;
    for (int i = wv; i < 256; i += 4) {
        int t = b*1024 + chunk*256 + i;
        float lgv = logits[(size_t)t*320 + r*64 + lane];
        float mx = lgv;
        for (int off = 32; off >= 1; off >>= 1) mx = fmaxf(mx, __shfl_xor(mx, off));
        float e = __expf(lgv - mx);
        float s = e;
        for (int off = 32; off >= 1; off >>= 1) s += __shfl_xor(s, off);
        acc += imp[t] * e / s;
    }
    __shared__ float red[4][64];
    red[wv][lane] = acc;
    __syncthreads();
    if (tid < 64)
        partial[((size_t)(r*8 + b)*4 + chunk)*64 + tid]
            = red[0][tid] + red[1][tid] + red[2][tid] + red[3][tid];
}

// Normalize, top-k (k=16 for routers 0,4; k=8 for 1,2,3), renormalize.
__global__ void topk_router(const float* __restrict__ partial,
                            float* __restrict__ tw, int* __restrict__ ti)
{
    int rb = blockIdx.x;           // r*8+b
    int r  = rb >> 3;
    int lane = threadIdx.x;        // 64 threads = 1 wave
    float v = partial[((size_t)rb*4 + 0)*64 + lane] + partial[((size_t)rb*4 + 1)*64 + lane]
            + partial[((size_t)rb*4 + 2)*64 + lane] + partial[((size_t)rb*4 + 3)*64 + lane];
    float s = v;
    for (int off = 32; off >= 1; off >>= 1) s += __shfl_xor(s, off);
    v = v / (s + 1e-8f);
    int k = (r == 0 || r == 4) ? 16 : 8;
    __shared__ float tv[16];
    __shared__ int   tix[16];
    float cur = v;
    for (int it = 0; it < k; ++it) {
        float bv = cur; int bi = lane;
        for (int off = 32; off >= 1; off >>= 1) {
            float ov = __shfl_xor(bv, off);
            int   oi = __shfl_xor(bi, off);
            if (ov > bv || (ov == bv && oi < bi)) { bv = ov; bi = oi; }
        }
        if (bi == lane) cur = -1e30f;
        if (lane == 0) { tv[it] = bv; tix[it] = bi; }
    }
    __syncthreads();
    float s2 = 0.f;
    for (int i = 0; i < k; ++i) s2 += tv[i];
    float inv = 1.f / (s2 + 1e-8f);
    if (lane < k) {
        tw[(size_t)rb*16 + lane] = tv[lane] * inv;
        ti[(size_t)rb*16 + lane] = tix[lane];
    }
}

// ======================================================================
// Fused expert combine: all 5 segments in one launch (blockIdx.z = seg).
// seg 0: neurons/tw0 k=16 -> hhm cols 0..255   (nInner=256, rs=512)
// seg 1: neurons/tw4 k=16 -> hhm cols 256..511
// seg 2..4: pool/tw1..3 k=8 -> qkv colOff {0,1024,2048} (nInner=1024, rs=TDN)
// ======================================================================
__global__ __launch_bounds__(256) void combine_all(
    const float* __restrict__ neurons, const float* __restrict__ pool,
    const float* __restrict__ tw, const int* __restrict__ ti,
    ush* __restrict__ hhmBh, ush* __restrict__ hhmBl,
    ush* __restrict__ qkvBh, ush* __restrict__ qkvBl)
{
    int seg = blockIdx.z;
    int b = blockIdx.y;
    const float* table;
    int twIdx, k, nInner, rowStride, colOff;
    ush *outhi, *outlo;
    long long sOut;
    if (seg < 2) {
        table = neurons; k = 16; nInner = 256; rowStride = 512;
        twIdx = (seg == 0) ? 0 : 4;
        colOff = (seg == 0) ? 0 : 256;
        outhi = hhmBh; outlo = hhmBl; sOut = (long long)2*EPE;
    } else {
        table = pool; k = 8; nInner = 1024; rowStride = TDN;
        twIdx = seg - 1;                       // 1,2,3
        colOff = (seg - 2)*1024;               // 0,1024,2048
        outhi = qkvBh; outlo = qkvBl; sOut = (long long)3*EPE;
    }
    const float* twp = tw + (size_t)(twIdx*Bn + b)*16;
    const int*   tip = ti + (size_t)(twIdx*Bn + b)*16;

    size_t e = ((size_t)blockIdx.x*256 + threadIdx.x)*4;
    float4 acc = {0.f, 0.f, 0.f, 0.f};
    for (int i = 0; i < k; ++i) {
        float w = twp[i];
        int  idx = tip[i];
        float4 t = *(const float4*)&table[(size_t)idx*EPE + e];
        acc.x += w*t.x; acc.y += w*t.y; acc.z += w*t.z; acc.w += w*t.w;
    }
    float vals[4] = {acc.x, acc.y, acc.z, acc.w};
    ushort4v h, l;
#pragma unroll
    for (int i = 0; i < 4; ++i) {
        ush a, b2; f2bf_split(vals[i], a, b2);
        h[i] = a; l[i] = b2;
    }
    int row = (int)(e / nInner), col = (int)(e % nInner);
    size_t dst = (size_t)b*sOut + (size_t)row*rowStride + colOff + col;
    *(ushort4v*)&outhi[dst] = h;
    *(ushort4v*)&outlo[dst] = l;
}

// ======================================================================
// MFMA bf16 flash attention, merged dual-q-tile, merged QKV input,
// split-plane output, setprio around MFMA (T5).
// ======================================================================
#define PADK 72

__global__ __launch_bounds__(256, 4) void attn_mfma_kernel(
    const ush* __restrict__ QKV,
    ush* __restrict__ Ohi, ush* __restrict__ Olo)
{
    int aa = blockIdx.x;                // 0..7
    int hh = blockIdx.y, b = blockIdx.z;
    int qt0 = aa, qt1 = 15 - aa;        // qt0 < qt1 always
    int tid  = threadIdx.x;
    int wave = tid >> 6, lane = tid & 63;
    int lr = lane & 15, lg = lane >> 4;

    __shared__ __align__(16) ush Kt[64][PADK];
    __shared__ __align__(16) ush Vt[64][PADK];   // Vt[d][kv]
    __shared__ __align__(16) ush Pt[64][PADK];

    const ush* Qr0 = QKV + ((size_t)b*Sn + (size_t)qt0*64 + wave*16 + lr)*TDN + hh*64;
    const ush* Qr1 = QKV + ((size_t)b*Sn + (size_t)qt1*64 + wave*16 + lr)*TDN + hh*64;
    short8 q0a = *(const short8*)&Qr0[lg*8];
    short8 q0b = *(const short8*)&Qr0[32 + lg*8];
    short8 q1a = *(const short8*)&Qr1[lg*8];
    short8 q1b = *(const short8*)&Qr1[32 + lg*8];

    f32x4 o0[4], o1[4];
    float m0[4], l0[4], m1[4], l1[4];
#pragma unroll
    for (int ct = 0; ct < 4; ++ct) {
        o0[ct] = (f32x4){0.f,0.f,0.f,0.f};
        o1[ct] = (f32x4){0.f,0.f,0.f,0.f};
    }
#pragma unroll
    for (int r = 0; r < 4; ++r) {
        m0[r] = -1e30f; l0[r] = 0.f;
        m1[r] = -1e30f; l1[r] = 0.f;
    }

    auto process = [&](short8 qa, short8 qb, f32x4 (&o)[4],
                       float (&m)[4], float (&l)[4], int qt, int kt) {
        f32x4 s[4];
        __builtin_amdgcn_s_setprio(1);
#pragma unroll
        for (int ct = 0; ct < 4; ++ct) {
            s[ct] = (f32x4){0.f,0.f,0.f,0.f};
            short8 k0 = *(const short8*)&Kt[ct*16 + lr][lg*8];
            short8 k1 = *(const short8*)&Kt[ct*16 + lr][32 + lg*8];
            s[ct] = __builtin_amdgcn_mfma_f32_16x16x32_bf16(qa, k0, s[ct], 0, 0, 0);
            s[ct] = __builtin_amdgcn_mfma_f32_16x16x32_bf16(qb, k1, s[ct], 0, 0, 0);
        }
        __builtin_amdgcn_s_setprio(0);
        float mx[4] = {-1e30f,-1e30f,-1e30f,-1e30f};
        int qg0 = qt*64 + wave*16 + lg*4;
#pragma unroll
        for (int ct = 0; ct < 4; ++ct) {
            int kvg = kt*64 + ct*16 + lr;
#pragma unroll
            for (int r = 0; r < 4; ++r) {
                float v = s[ct][r] * 0.125f;
                if (kt == qt && kvg > qg0 + r) v = -1e30f;
                s[ct][r] = v;
                mx[r] = fmaxf(mx[r], v);
            }
        }
#pragma unroll
        for (int r = 0; r < 4; ++r) {
            mx[r] = fmaxf(mx[r], __shfl_xor(mx[r], 1));
            mx[r] = fmaxf(mx[r], __shfl_xor(mx[r], 2));
            mx[r] = fmaxf(mx[r], __shfl_xor(mx[r], 4));
            mx[r] = fmaxf(mx[r], __shfl_xor(mx[r], 8));
        }
        float corr[4], ps[4] = {0.f,0.f,0.f,0.f};
#pragma unroll
        for (int r = 0; r < 4; ++r) {
            float mn = fmaxf(m[r], mx[r]);
            corr[r] = __expf(m[r] - mn);
            m[r] = mn;
        }
#pragma unroll
        for (int ct = 0; ct < 4; ++ct)
#pragma unroll
            for (int r = 0; r < 4; ++r) {
                float e = __expf(s[ct][r] - m[r]);
                s[ct][r] = e;
                ps[r] += e;
            }
#pragma unroll
        for (int r = 0; r < 4; ++r) {
            ps[r] += __shfl_xor(ps[r], 1);
            ps[r] += __shfl_xor(ps[r], 2);
            ps[r] += __shfl_xor(ps[r], 4);
            ps[r] += __shfl_xor(ps[r], 8);
            l[r] = l[r]*corr[r] + ps[r];
#pragma unroll
            for (int ct = 0; ct < 4; ++ct) o[ct][r] *= corr[r];
        }
#pragma unroll
        for (int ct = 0; ct < 4; ++ct)
#pragma unroll
            for (int r = 0; r < 4; ++r)
                Pt[wave*16 + lg*4 + r][ct*16 + lr] = f2bf(s[ct][r]);
        short8 pa0 = *(const short8*)&Pt[wave*16 + lr][lg*8];
        short8 pa1 = *(const short8*)&Pt[wave*16 + lr][32 + lg*8];
        __builtin_amdgcn_s_setprio(1);
#pragma unroll
        for (int ct = 0; ct < 4; ++ct) {
            short8 v0 = *(const short8*)&Vt[ct*16 + lr][lg*8];
            short8 v1 = *(const short8*)&Vt[ct*16 + lr][32 + lg*8];
            o[ct] = __builtin_amdgcn_mfma_f32_16x16x32_bf16(pa0, v0, o[ct], 0, 0, 0);
            o[ct] = __builtin_amdgcn_mfma_f32_16x16x32_bf16(pa1, v1, o[ct], 0, 0, 0);
        }
        __builtin_amdgcn_s_setprio(0);
    };

    for (int kt = 0; kt <= qt1; ++kt) {
        __syncthreads();
        const ush* Kb = QKV + ((size_t)b*Sn + (size_t)kt*64)*TDN + 1024 + hh*64;
        const ush* Vb = QKV + ((size_t)b*Sn + (size_t)kt*64)*TDN + 2048 + hh*64;
#pragma unroll
        for (int it2 = 0; it2 < 2; ++it2) {
            int idx = tid + it2*256;
            int kv = idx >> 3, d0 = (idx & 7)*8;
            *(short8*)&Kt[kv][d0] = *(const short8*)&Kb[(size_t)kv*TDN + d0];
        }
#pragma unroll
        for (int it2 = 0; it2 < 2; ++it2) {
            int idx = tid + it2*256;
            int kv = idx & 63, d0 = (idx >> 6)*8;
            short8 w = *(const short8*)&Vb[(size_t)kv*TDN + d0];
#pragma unroll
            for (int e = 0; e < 8; ++e) Vt[d0+e][kv] = (ush)w[e];
        }
        __syncthreads();

        if (kt <= qt0) process(q0a, q0b, o0, m0, l0, qt0, kt);
        process(q1a, q1b, o1, m1, l1, qt1, kt);
    }

    {
        size_t base = ((size_t)b*Sn + (size_t)qt0*64 + wave*16 + lg*4)*Dn + hh*64 + lr;
#pragma unroll
        for (int r = 0; r < 4; ++r) {
            float inv = 1.f / l0[r];
#pragma unroll
            for (int ct = 0; ct < 4; ++ct) {
                float val = o0[ct][r] * inv;
                ush h, lo2; f2bf_split(val, h, lo2);
                Ohi[base + (size_t)r*Dn + ct*16] = h;
                Olo[base + (size_t)r*Dn + ct*16] = lo2;
            }
        }
    }
    {
        size_t base = ((size_t)b*Sn + (size_t)qt1*64 + wave*16 + lg*4)*Dn + hh*64 + lr;
#pragma unroll
        for (int r = 0; r < 4; ++r) {
            float inv = 1.f / l1[r];
#pragma unroll
            for (int ct = 0; ct < 4; ++ct) {
                float val = o1[ct][r] * inv;
                ush h, lo2; f2bf_split(val, h, lo2);
                Ohi[base + (size_t)r*Dn + ct*16] = h;
                Olo[base + (size_t)r*Dn + ct*16] = lo2;
            }
        }
    }
}

// ======================================================================
// Knowledge memory, wave-per-token, bf16 approx scores (full 8192 tokens).
// Proven monolithic version (round-12 response, 601 us, passed).
// ======================================================================
__global__ __launch_bounds__(256) void mem_topk_wave(
    const ush* __restrict__ ksc,     // [8192][4096] bf16 scores
    const float* __restrict__ hm,    // [8192][256] f32
    const float* __restrict__ kK,    // [4096][256]
    const float* __restrict__ kV,    // [4096][1024]
    float* __restrict__ out)
{
    int wave = threadIdx.x >> 6, lane = threadIdx.x & 63;
    int t = blockIdx.x*4 + wave;            // global token 0..8191
    const ush* row = ksc + (size_t)t*NKn;

    float v[64];
    float lmax = -3e38f;
#pragma unroll
    for (int j8 = 0; j8 < 8; ++j8) {
        short8 w = *(const short8*)&row[lane*64 + j8*8];
#pragma unroll
        for (int e = 0; e < 8; ++e) {
            float f = bf2f((ush)w[e]);
            v[j8*8+e] = f;
            lmax = fmaxf(lmax, f);
        }
    }

    float sv = lmax;
#pragma unroll
    for (int k = 2; k <= 64; k <<= 1) {
#pragma unroll
        for (int j = k >> 1; j >= 1; j >>= 1) {
            float ov = __shfl_xor(sv, j);
            bool keepLarger = (((lane & j) == 0) == ((lane & k) == 0));
            float mx = fmaxf(sv, ov), mn = fminf(sv, ov);
            sv = keepLarger ? mx : mn;
        }
    }
    float T = __shfl(sv, 15);   // 16th largest lane max

    __shared__ float s_cv[4][64];
    __shared__ int   s_cix[4][64];
    __shared__ float s_cs[4][16];
    __shared__ int   s_tix[4][16];

    int cnt = 0;
#pragma unroll
    for (int j = 0; j < 64; ++j) cnt += (v[j] >= T) ? 1 : 0;
    int pre = cnt;
#pragma unroll
    for (int off2 = 1; off2 < 64; off2 <<= 1) {
        int og = __shfl_up(pre, off2);
        if (lane >= off2) pre += og;
    }
    int C = __shfl(pre, 63);
    int base = pre - cnt;

    if (C <= 64) {
        int pos = base;
#pragma unroll
        for (int j = 0; j < 64; ++j) {
            if (v[j] >= T) {
                s_cv[wave][pos] = v[j];
                s_cix[wave][pos] = lane*64 + j;
                ++pos;
            }
        }
        float cv2 = (lane < C) ? s_cv[wave][lane] : -3e38f;
        int   cix = (lane < C) ? s_cix[wave][lane] : 0x7fffffff;
#pragma unroll
        for (int k = 2; k <= 64; k <<= 1) {
#pragma unroll
            for (int j = k >> 1; j >= 1; j >>= 1) {
                float ov = __shfl_xor(cv2, j);
                int   oi = __shfl_xor(cix, j);
                bool amLarger = (cv2 > ov) || (cv2 == ov && cix < oi);
                bool keepLarger = (((lane & j) == 0) == ((lane & k) == 0));
                if (amLarger != keepLarger) { cv2 = ov; cix = oi; }
            }
        }
        if (lane < 16) s_tix[wave][lane] = cix;
    } else {
        for (int it = 0; it < 16; ++it) {
            float bv = -3e38f; int bi = 0x7fffffff;
#pragma unroll
            for (int j = 0; j < 64; ++j) {
                int n = lane*64 + j;
                if (v[j] > bv || (v[j] == bv && n < bi)) { bv = v[j]; bi = n; }
            }
#pragma unroll
            for (int off2 = 32; off2 >= 1; off2 >>= 1) {
                float ov = __shfl_xor(bv, off2);
                int   oi = __shfl_xor(bi, off2);
                if (ov > bv || (ov == bv && oi < bi)) { bv = ov; bi = oi; }
            }
            if (lane == 0) s_tix[wave][it] = bi;
#pragma unroll
            for (int j = 0; j < 64; ++j)
                if (lane*64 + j == bi) v[j] = -3e38f;
        }
    }

    int c = lane >> 2, q = lane & 3;
    int kidx = s_tix[wave][c];
    const float* kr = kK + (size_t)kidx*Rn;
    const float* hr = hm + (size_t)t*Rn;
    float d = 0.f;
#pragma unroll
    for (int j4 = 0; j4 < 16; ++j4) {
        float4 a  = *(const float4*)&hr[q*64 + j4*4];
        float4 bb = *(const float4*)&kr[q*64 + j4*4];
        d += a.x*bb.x + a.y*bb.y + a.z*bb.z + a.w*bb.w;
    }
    d += __shfl_xor(d, 1);
    d += __shfl_xor(d, 2);
    if (q == 0) s_cs[wave][c] = d * 0.0625f;      // 1/sqrt(256)

    float cv = (lane < 16) ? s_cs[wave][lane] : -3e38f;
    int   ck = (lane < 16) ? s_tix[wave][lane] : 0x7fffffff;
    float sv8[8]; int si[8];
#pragma unroll
    for (int it = 0; it < 8; ++it) {
        float bv = cv; int bk = ck;
#pragma unroll
        for (int off2 = 32; off2 >= 1; off2 >>= 1) {
            float ov = __shfl_xor(bv, off2);
            int   ok = __shfl_xor(bk, off2);
            if (ov > bv || (ov == bv && ok < bk)) { bv = ov; bk = ok; }
        }
        sv8[it] = bv; si[it] = bk;
        if (ck == bk) cv = -3e38f;
    }

    float mxv = sv8[0];
#pragma unroll
    for (int kx = 1; kx < 8; ++kx) mxv = fmaxf(mxv, sv8[kx]);
    float p[8]; float sum = 0.f;
#pragma unroll
    for (int kx = 0; kx < 8; ++kx) { p[kx] = __expf(sv8[kx] - mxv); sum += p[kx]; }
    float invs = 1.f / sum;
    float4 acc0 = {0,0,0,0}, acc1 = {0,0,0,0}, acc2 = {0,0,0,0}, acc3 = {0,0,0,0};
#pragma unroll
    for (int kx = 0; kx < 8; ++kx) {
        float pk = p[kx]*invs;
        const float* vp = kV + (size_t)si[kx]*Dn + lane*16;
        float4 v0 = *(const float4*)(vp + 0);
        float4 v1 = *(const float4*)(vp + 4);
        float4 v2 = *(const float4*)(vp + 8);
        float4 v3 = *(const float4*)(vp + 12);
        acc0.x += pk*v0.x; acc0.y += pk*v0.y; acc0.z += pk*v0.z; acc0.w += pk*v0.w;
        acc1.x += pk*v1.x; acc1.y += pk*v1.y; acc1.z += pk*v1.z; acc1.w += pk*v1.w;
        acc2.x += pk*v2.x; acc2.y += pk*v2.y; acc2.z += pk*v2.z; acc2.w += pk*v2.w;
        acc3.x += pk*v3.x; acc3.y += pk*v3.y; acc3.z += pk*v3.z; acc3.w += pk*v3.w;
    }
    float* op = out + (size_t)t*Dn + lane*16;
    float4 c0 = *(const float4*)(op + 0);
    float4 c1 = *(const float4*)(op + 4);
    float4 c2 = *(const float4*)(op + 8);
    float4 c3 = *(const float4*)(op + 12);
    c0.x+=acc0.x; c0.y+=acc0.y; c0.z+=acc0.z; c0.w+=acc0.w;
    c1.x+=acc1.x; c1.y+=acc1.y; c1.z+=acc1.z; c1.w+=acc1.w;
    c2.x+=acc2.x; c2.y+=acc2.y; c2.z+=acc2.z; c2.w+=acc2.w;
    c3.x+=acc3.x; c3.y+=acc3.y; c3.z+=acc3.z; c3.w+=acc3.w;
    *(float4*)(op + 0)  = c0;
    *(float4*)(op + 4)  = c1;
    *(float4*)(op + 8)  = c2;
    *(float4*)(op + 12) = c3;
}

// ======================================================================
extern "C" void kernel_launch(void* const* d_in, const int* in_sizes, int n_in,
                              void* d_out, int out_size, void* d_ws, size_t ws_size,
                              hipStream_t stream)
{
    const float* x          = (const float*)d_in[0];
    const float* imp        = (const float*)d_in[1];
    const float* compress_w = (const float*)d_in[2];
    const float* expQ_w     = (const float*)d_in[3];
    const float* expK_w     = (const float*)d_in[4];
    const float* expV_w     = (const float*)d_in[5];
    const float* memory_w   = (const float*)d_in[6];
    const float* neurons    = (const float*)d_in[7];   // [64, D, R]
    const float* pool       = (const float*)d_in[8];   // [64, R, D]
    const float* kK         = (const float*)d_in[9];   // [4096, R]
    const float* kV         = (const float*)d_in[10];  // [4096, D]
    const float* Wo         = (const float*)d_in[11];  // [D, D]
    float* out = (float*)d_out;

    // ---- workspace layout (~195 MB) ----
    char* ws = (char*)d_ws;
    size_t off = 0;
    auto alloc = [&](size_t bytes) {
        size_t o = off; off = (off + bytes + 255) & ~(size_t)255; return (void*)(ws + o);
    };
    ush* xqh    = (ush*)alloc((size_t)TOK*Dn*2);
    ush* xql    = (ush*)alloc((size_t)TOK*Dn*2);
    ush* wcatqh = (ush*)alloc((size_t)320*Dn*2);
    ush* wcatql = (ush*)alloc((size_t)320*Dn*2);
    ush* Woqh   = (ush*)alloc((size_t)Dn*Dn*2);
    ush* Woql   = (ush*)alloc((size_t)Dn*Dn*2);
    ush* kKqh   = (ush*)alloc((size_t)NKn*Rn*2);
    ush* kKql   = (ush*)alloc((size_t)NKn*Rn*2);
    float* logits  = (float*)alloc((size_t)TOK*320*4);
    float* partial = (float*)alloc((size_t)40*4*64*4);
    float* tw      = (float*)alloc((size_t)5*Bn*16*4);
    int*   ti      = (int*)  alloc((size_t)5*Bn*16*4);
    ush* hhmBh = (ush*)alloc((size_t)Bn*2*EPE*2);   // [b][1024][512] K x (h|hm)
    ush* hhmBl = (ush*)alloc((size_t)Bn*2*EPE*2);
    ush* qkvBh = (ush*)alloc((size_t)Bn*3*EPE*2);   // [b][256][3072] K x (Q|K|V)
    ush* qkvBl = (ush*)alloc((size_t)Bn*3*EPE*2);
    ush* hqh   = (ush*)alloc((size_t)TOK*Rn*2);
    ush* hql   = (ush*)alloc((size_t)TOK*Rn*2);
    float* hm  = (float*)alloc((size_t)TOK*Rn*4);
    ush* hmqh  = (ush*)alloc((size_t)TOK*Rn*2);
    ush* QKVb  = (ush*)alloc((size_t)TOK*TDN*2);    // 48 MB
    ush* Obqh  = (ush*)alloc((size_t)TOK*Dn*2);     // 16 MB
    ush* Obql  = (ush*)alloc((size_t)TOK*Dn*2);     // 16 MB
    // ksc bf16 [8192][4096] = 64MB aliases QKVb+Obqh (dead after Wo GEMM)
    ush* ksc = QKVb;
    (void)ws_size; (void)in_sizes; (void)n_in; (void)out_size;

    // ---- 0. pre-split conversions (2 launches) ----
    convert3<<<10240, 256, 0, stream>>>(
        x, xqh, xql, (long long)TOK*Dn/4,
        Wo, Woqh, Woql, (long long)Dn*Dn/4,
        kK, kKqh, kKql, (long long)NKn*Rn/4);
    convert_w5<<<dim3(64, 5), 256, 0, stream>>>(
        compress_w, expQ_w, expK_w, expV_w, memory_w, wcatqh, wcatql);

    // ---- 1. routers: 64-tile GEMM (640 blocks), fused post, topk ----
    gemm64<<<dim3(5, 128, 1), 256, 0, stream>>>(
        xqh, xql, wcatqh, wcatql, logits, nullptr, nullptr, nullptr,
        320, Dn, 0LL, 0LL, 0LL, 0LL, 1.f, 0 /*NK*/, 3, 0);
    router_post<<<160, 256, 0, stream>>>(logits, imp, partial);
    topk_router<<<40, 64, 0, stream>>>(partial, tw, ti);

    // ---- 2. fused expert combines (one launch, 5 segments) ----
    combine_all<<<dim3(EPE/1024, Bn, 5), 256, 0, stream>>>(
        neurons, pool, tw, ti, hhmBh, hhmBl, qkvBh, qkvBl);

    // ---- 3. h+hm merged (N=512, 64-tile, 1024 blocks) ----
    gemm64<<<dim3(8, 16, Bn), 256, 0, stream>>>(
        xqh, xql, hhmBh, hhmBl, hqh, hql, hm, hmqh,
        512, Dn, (long long)Sn*Dn, (long long)2*EPE,
        (long long)Sn*Rn, (long long)Sn*Rn, 1.f, 1 /*KN*/, 3, 1);

    // ---- 4. merged QKV (N=3072, 128-tile, 3072 blocks, bf16 out) ----
    gemm_pre<<<dim3(TDN/64, Sn/128, Bn), 256, 0, stream>>>(
        hqh, hql, qkvBh, qkvBl, QKVb, nullptr,
        Sn, TDN, Rn, (long long)Sn*Rn, (long long)3*EPE, (long long)Sn*TDN,
        1.f, 1 /*KN*/, 3, 1, 0);

    // ---- 5. causal flash attention (merged QKV in, split-plane out) ----
    attn_mfma_kernel<<<dim3(8, NHn, Bn), 256, 0, stream>>>(QKVb, Obqh, Obql);

    // ---- 6. output projection: d_out = O @ Wo^T (2 passes, gridSwap) ----
    gemm_pre<<<dim3(TOK/128, Dn/64, 1), 256, 0, stream>>>(
        Obqh, Obql, Woqh, Woql, out, nullptr,
        TOK, Dn, Dn, 0LL, 0LL, 0LL, 1.f, 0 /*NK*/, 2, 0, 1 /*gridSwap*/);

    // ---- 7. knowledge memory: one GEMM (M=8192) + one topk launch ----
    gemm_pre<<<dim3(NKn/64, TOK/128, 1), 256, 0, stream>>>(
        hmqh, nullptr, kKqh, nullptr, ksc, nullptr,
        TOK, NKn, Rn, 0LL, 0LL, 0LL, 0.0625f, 0 /*NK*/, 1, 1 /*bf16*/, 0);
    mem_topk_wave<<<2048, 256, 0, stream>>>(ksc, hm, kK, kV, out);
}